// Round 8
// baseline (399.403 us; speedup 1.0000x reference)
//
#include <hip/hip_runtime.h>
#include <hip/hip_bf16.h>

#define H 4
#define D 32
#define HD 128
#define ND 10000
#define NG 30000
#define E_DG 150000
#define E_GD 150000
#define E_GG 300000
#define NE (E_DG + E_GD + E_GG)
#define EG (E_DG + E_GG)   // edges into gene nodes
#define NLAYER 2
#define NBG 30             // ceil(NG/1024)
#define NBD 10             // ceil(ND/1024)
#define NSCAN (NBG + NBD)
#define OCG 640            // gene table cols:   [q|k1|v1|k2|v2]
#define OCD 384            // disease table cols:[q|k0|v0]
#define GOFF ((size_t)ND * OCD)   // gene rows offset in unified table
#define NSCAT 2344         // histogram blocks in prep0
#define NQUAD 625          // 4-mtile GEMM blocks (2500 mtiles / 4)
#define XLSTRIDE 136       // LDS A-row stride in f16 (mod-32-words = 4 -> 2x/bank-quad)

typedef _Float16 f16;
typedef __attribute__((ext_vector_type(2))) _Float16 f16x2;
typedef __attribute__((ext_vector_type(4))) _Float16 f16x4;
typedef __attribute__((ext_vector_type(8))) _Float16 f16x8;
typedef __attribute__((ext_vector_type(8))) unsigned short u16x8;
typedef __attribute__((ext_vector_type(4))) float f32x4;

__device__ __forceinline__ float bu(unsigned short u) {
    return __uint_as_float(((unsigned)u) << 16);
}
// raw input load with dtype branch (isf32 wave-uniform)
__device__ __forceinline__ float ldraw(const void* p, size_t i, bool isf32) {
    return isf32 ? ((const float*)p)[i] : bu(((const unsigned short*)p)[i]);
}
__device__ __forceinline__ float gelu(float v) {
    const float c = 0.79788456080286536f * (v + 0.044715f * v * v * v);
    return 0.5f * v * (1.0f + tanhf(c));
}

// ---------------------------------------------------------------------------
// Combined-weight fold (rel matrices + prel*scale*log2e into K), raw inputs.
// W reads vectorized (32 contiguous elems -> 4x16B / 8x16B loads).
__device__ __forceinline__ void combine_one(
    int idx, int GENE, bool isf32,
    const void* W, const void* bvec,
    const void* arel, const void* mrel, const void* prel,
    f16* __restrict__ Wp, float* __restrict__ bp) {
    const int OC = GENE ? OCG : OCD;
    const int l = idx / (OC * 128);
    const int rem = idx - l * OC * 128;
    const int col = rem >> 7;
    const int d = rem & 127;
    const int g = col >> 7;           // 0=q, 1/3=k, 2/4=v
    const int jj = col & 127;
    const int h = jj >> 5, f = jj & 31;
    const size_t wbase = (size_t)l * 128 * 384;
    const size_t bbase = (size_t)l * 384;
    float val, bv = 0.f;
    if (g == 0) {
        val = ldraw(W, wbase + d * 384 + 128 + jj, isf32);
        bv = ldraw(bvec, bbase + 128 + jj, isf32);
    } else {
        const int et = GENE ? ((g <= 2) ? 1 : 2) : 0;
        const bool isk = (g & 1);
        const void* mat = isk ? arel : mrel;
        const size_t mbase = (((size_t)(l * 3 + et) * H + h) << 10) + f;
        const int sb = isk ? 0 : 256;
        const size_t wrow = wbase + d * 384 + sb + h * 32;   // 32 contiguous elems
        float wv[32];
        if (isf32) {
            const float* wp = (const float*)W + wrow;
#pragma unroll
            for (int j = 0; j < 8; j++) {
                const f32x4 u = *(const f32x4*)(wp + j * 4);
#pragma unroll
                for (int t = 0; t < 4; t++) wv[j * 4 + t] = u[t];
            }
        } else {
            const unsigned short* wp = (const unsigned short*)W + wrow;
#pragma unroll
            for (int j = 0; j < 4; j++) {
                const u16x8 u = *(const u16x8*)(wp + j * 8);
#pragma unroll
                for (int t = 0; t < 8; t++) wv[j * 8 + t] = bu(u[t]);
            }
        }
        val = 0.f;
#pragma unroll
        for (int dd = 0; dd < 32; dd++)
            val += wv[dd] * ldraw(mat, mbase + dd * 32, isf32);
        if (d == 0)
            for (int dd = 0; dd < 32; dd++)
                bv += ldraw(bvec, bbase + sb + h * 32 + dd, isf32) *
                      ldraw(mat, mbase + dd * 32, isf32);
        if (isk) {
            const float sc = ldraw(prel, (size_t)(l * 3 + et) * H + h, isf32) *
                             (0.17677669529663689f * 1.4426950408889634f);
            val *= sc;
            bv *= sc;
        }
    }
    Wp[(size_t)l * 4 * OC * 32 + ((size_t)(d >> 5) * OC + col) * 32 + (d & 31)] = (f16)val;
    if (d == 0) bp[l * OC + col] = bv;
}

// ---------------------------------------------------------------------------
// Mega-prep: self-detect dtype, fold+pack all weights, zero ready+scan_done,
// convert bout, compute sigmoid(skip) gates, publish flag. Blocks >=1281 run
// the histogram fused in (cnt zeroed by hipMemsetAsync before this kernel),
// and capture each edge's within-bucket rank from the atomicAdd return value.
__global__ __launch_bounds__(256) void k_prep0(
    const void* x0,
    const void* wkqvd_r, const void* bkqvd_r,
    const void* wkqvg_r, const void* bkqvg_r,
    const void* arel_r, const void* mrel_r, const void* prel_r,
    const void* woutd_r, const void* woutg_r,
    const void* boutd_r, const void* boutg_r,
    const void* skipd_r, const void* skipg_r,
    f16* __restrict__ Wp_d, float* __restrict__ bp_d,
    f16* __restrict__ Wp_g, float* __restrict__ bp_g,
    f16* __restrict__ Wpod, f16* __restrict__ Wpog,
    float* __restrict__ boutc_d, float* __restrict__ boutc_g,
    float* __restrict__ gates, int* __restrict__ flag,
    const int* __restrict__ dst_dg, const int* __restrict__ dst_gg,
    const int* __restrict__ dst_gd,
    int* __restrict__ cnt_g, int* __restrict__ cnt_d,
    int* __restrict__ rank, int* __restrict__ ready) {
    const int tid = threadIdx.x;
    const int b = blockIdx.x;
    if (b >= 1281) {
        // fused histogram + rank capture
        const int i = (b - 1281) * 256 + tid;
        if (i < E_DG) rank[i] = atomicAdd(cnt_g + dst_dg[i], 1);
        else if (i < EG) rank[i] = atomicAdd(cnt_g + dst_gg[i - E_DG], 1);
        else if (i < NE) rank[i] = atomicAdd(cnt_d + dst_gd[i - EG], 1);
        return;
    }
    __shared__ int sbad;
    if (tid == 0) sbad = 0;
    __syncthreads();
    {
        const unsigned short* xs = (const unsigned short*)x0;
        int bad = 0;
        for (int i = tid; i < 1024; i += 256)
            if (!(fabsf(bu(xs[i])) < 1e6f)) bad = 1;
        if (bad) sbad = 1;   // benign race
    }
    __syncthreads();
    const bool isf32 = (sbad != 0);

    if (b < 1280) {
        int idx = b * 256 + tid;
        const int nd = NLAYER * OCD * 128;
        const int ng = NLAYER * OCG * 128;
        const int np = 2 * NLAYER * 128 * 128;
        if (idx < nd) {
            combine_one(idx, 0, isf32, wkqvd_r, bkqvd_r, arel_r, mrel_r, prel_r, Wp_d, bp_d);
        } else if ((idx -= nd) < ng) {
            combine_one(idx, 1, isf32, wkqvg_r, bkqvg_r, arel_r, mrel_r, prel_r, Wp_g, bp_g);
        } else if ((idx -= ng) < np) {
            const int type = idx >= NLAYER * 128 * 128;
            int rem = idx - type * NLAYER * 128 * 128;
            const int l = rem / (128 * 128);
            rem -= l * 128 * 128;
            const int d = rem >> 7, col = rem & 127;
            const float w = ldraw(type ? woutg_r : woutd_r,
                                  (size_t)l * 128 * 128 + d * 128 + col, isf32);
            f16* out = (type ? Wpog : Wpod) +
                ((size_t)l * 4 + (d >> 5)) * 128 * 32 + col * 32 + (d & 31);
            *out = (f16)w;
        }
    } else {   // b == 1280
        if (tid < NSCAN) ready[tid] = 0;
        if (tid == 63) ready[63] = 0;   // scan_done counter
        if (tid == 0) {
            flag[0] = isf32 ? 1 : 0;
            gates[0] = 1.f / (1.f + expf(-ldraw(skipd_r, 0, isf32)));
            gates[1] = 1.f / (1.f + expf(-ldraw(skipg_r, 0, isf32)));
            gates[2] = 1.f / (1.f + expf(-ldraw(skipd_r, 1, isf32)));
            gates[3] = 1.f / (1.f + expf(-ldraw(skipg_r, 1, isf32)));
        }
        for (int i = tid; i < NLAYER * 128; i += 256) {
            boutc_d[i] = ldraw(boutd_r, i, isf32);
            boutc_g[i] = ldraw(boutg_r, i, isf32);
        }
    }
}

// ---------------------------------------------------------------------------
// 4-mtile KQV GEMM over a 64-row LDS A tile. Each wave loads a 64-col B
// panel ONCE into registers and applies it to all 4 mtiles. Swapped-mfma
// layout (C^T): row=lane&15, 4 consecutive cols per acc reg -> f16x4 stores.
__device__ __forceinline__ void kqv_block_4mt(
    const f16* xls, int tid, int mt0,
    const f16* __restrict__ Wpd, const float* __restrict__ bpd,
    const f16* __restrict__ Wpg, const float* __restrict__ bpg,
    f16* __restrict__ tab) {
    const int wv = tid >> 6, lane = tid & 63;
    const int r = lane & 15, q4 = lane >> 4;
    const bool g0 = (mt0 * 16 >= ND);
    const bool g3 = ((mt0 + 3) * 16 >= ND);
    if (g0 == g3) {
        // uniform-type quad: B-reuse path
        const bool gene = g0;
        const int OC = gene ? OCG : OCD;
        const f16* Wp = gene ? Wpg : Wpd;
        const float* bias = gene ? bpg : bpd;
        f16* out = gene ? (tab + GOFF) : tab;
        const int trow0 = mt0 * 16 - (gene ? ND : 0);
        const int nt = gene ? 10 : 6;
        for (int ntl = wv; ntl < nt; ntl += 4) {
            const int col0 = ntl << 6;
            f16x8 B[4][4];
#pragma unroll
            for (int kb = 0; kb < 4; kb++) {
                const f16* wb = Wp + ((size_t)kb * OC + col0 + r) * 32 + q4 * 8;
#pragma unroll
                for (int t = 0; t < 4; t++) B[kb][t] = *(const f16x8*)(wb + t * 512);
            }
#pragma unroll 1
            for (int mtl = 0; mtl < 4; mtl++) {
                f32x4 acc[4];
                acc[0] = acc[1] = acc[2] = acc[3] = (f32x4){0.f, 0.f, 0.f, 0.f};
#pragma unroll
                for (int kb = 0; kb < 4; kb++) {
                    const f16x8 a = *(const f16x8*)(xls + (mtl * 16 + r) * XLSTRIDE + kb * 32 + q4 * 8);
#pragma unroll
                    for (int t = 0; t < 4; t++)
                        acc[t] = __builtin_amdgcn_mfma_f32_16x16x32_f16(B[kb][t], a, acc[t], 0, 0, 0);
                }
#pragma unroll
                for (int t = 0; t < 4; t++) {
                    const int col = col0 + t * 16 + q4 * 4;
                    const f32x4 bb = *(const f32x4*)(bias + col);
                    f16x4 o;
#pragma unroll
                    for (int reg = 0; reg < 4; reg++)
                        o[reg] = (f16)(acc[t][reg] + bb[reg]);
                    *(f16x4*)(out + (size_t)(trow0 + mtl * 16 + r) * OC + col) = o;
                }
            }
        }
    } else {
        // mixed quad (1 block at the d/g boundary): per-mtile path
        for (int mtl = 0; mtl < 4; mtl++) {
            const int node0 = (mt0 + mtl) * 16;
            const bool gene = (node0 >= ND);
            const int OC = gene ? OCG : OCD;
            const f16* Wp = gene ? Wpg : Wpd;
            const float* bias = gene ? bpg : bpd;
            f16* out = gene ? (tab + GOFF) : tab;
            const int trow0 = node0 - (gene ? ND : 0);
            const int nt = gene ? 10 : 6;
            for (int ntl = wv; ntl < nt; ntl += 4) {
                const int col0 = ntl << 6;
                f32x4 acc[4];
                acc[0] = acc[1] = acc[2] = acc[3] = (f32x4){0.f, 0.f, 0.f, 0.f};
#pragma unroll
                for (int kb = 0; kb < 4; kb++) {
                    const f16x8 a = *(const f16x8*)(xls + (mtl * 16 + r) * XLSTRIDE + kb * 32 + q4 * 8);
                    const f16* wb = Wp + ((size_t)kb * OC + col0 + r) * 32 + q4 * 8;
#pragma unroll
                    for (int t = 0; t < 4; t++) {
                        const f16x8 bt = *(const f16x8*)(wb + t * 512);
                        acc[t] = __builtin_amdgcn_mfma_f32_16x16x32_f16(bt, a, acc[t], 0, 0, 0);
                    }
                }
#pragma unroll
                for (int t = 0; t < 4; t++) {
                    const int col = col0 + t * 16 + q4 * 4;
                    const f32x4 bb = *(const f32x4*)(bias + col);
                    f16x4 o;
#pragma unroll
                    for (int reg = 0; reg < 4; reg++)
                        o[reg] = (f16)(acc[t][reg] + bb[reg]);
                    *(f16x4*)(out + (size_t)(trow0 + r) * OC + col) = o;
                }
            }
        }
    }
}

// ---------------------------------------------------------------------------
// Fused: decoupled-lookback scan (blocks [0,NSCAN)) + layer-0 KQV GEMM with
// scatter epilogue (blocks [NSCAN,..)). Scan blocks publish rp then release
// via ready[63]. Each GEMM block, AFTER its tile (~15-20us, scan done in ~5),
// does one mostly-satisfied poll of ready[63] and scatters a 625-block-
// strided slice of the 600k edges (~4/thread over 160k threads) -- right
// worker count (r7 lesson: 40 workers too few), tiny poller count (r4
// lesson: 2344 pollers too many). Scan blocks have lowest blockIdx so
// in-order dispatch keeps the lookback deadlock-free; co-residency (665
// blocks < 2048 slots) guarantees scatter's forward progress.
__global__ __launch_bounds__(256) void k_scangemm0(
    const int* __restrict__ cnt_g, const int* __restrict__ cnt_d,
    int* __restrict__ ready,
    int* __restrict__ rp_g, int* __restrict__ rp_d,
    const void* xd_r, const void* xg_r, const int* __restrict__ flag,
    const f16* __restrict__ Wpd, const float* __restrict__ bpd,
    const f16* __restrict__ Wpg, const float* __restrict__ bpg,
    f16* __restrict__ tab,
    const int* __restrict__ src_dg, const int* __restrict__ dst_dg,
    const int* __restrict__ src_gg, const int* __restrict__ dst_gg,
    const int* __restrict__ src_gd, const int* __restrict__ dst_gd,
    const int* __restrict__ rank,
    int* __restrict__ edges_g, int* __restrict__ edges_d) {
    __shared__ int sdata[256];
    __shared__ int red2[256];
    __shared__ int s_off;
    __shared__ f16 xls[64 * XLSTRIDE];
    const int tid = threadIdx.x;
    if (blockIdx.x < NSCAN) {
        const int b = blockIdx.x;
        const bool isg = (b < NBG);
        const int* cnt = isg ? cnt_g : cnt_d;
        int* rp = isg ? rp_g : rp_d;
        const int n = isg ? NG : ND;
        const int lb = isg ? b : (b - NBG);
        const int i0 = lb * 1024 + tid * 4;
        int v[4];
        int t = 0;
#pragma unroll
        for (int j = 0; j < 4; j++) {
            v[j] = (i0 + j < n) ? cnt[i0 + j] : 0;
            t += v[j];
        }
        sdata[tid] = t;
        __syncthreads();
        for (int d = 1; d < 256; d <<= 1) {
            const int u = (tid >= d) ? sdata[tid - d] : 0;
            __syncthreads();
            sdata[tid] += u;
            __syncthreads();
        }
        const int total = sdata[255];
        if (tid == 0) atomicExch(&ready[b], total + 1);
        const int p0 = isg ? 0 : NBG;
        const int npred = b - p0;
        int part = 0;
        for (int i = tid; i < npred; i += 256) {
            int vv;
            do { vv = atomicAdd(&ready[p0 + i], 0); } while (vv == 0);
            part += vv - 1;
        }
        red2[tid] = part;
        __syncthreads();
        for (int d = 128; d > 0; d >>= 1) {
            if (tid < d) red2[tid] += red2[tid + d];
            __syncthreads();
        }
        if (tid == 0) s_off = red2[0];
        __syncthreads();
        int run = s_off + sdata[tid] - t;
#pragma unroll
        for (int j = 0; j < 4; j++) {
            if (i0 + j < n) {
                run += v[j];
                rp[i0 + j + 1] = run;
            }
        }
        if (tid == 0 && lb == 0) rp[0] = 0;
        // release: make rp device-visible, then bump scan_done
        __threadfence();
        __syncthreads();
        if (tid == 0) atomicAdd(&ready[63], 1);
        return;
    }
    // ---- gemm0: 4 mtiles, 64-row LDS A stage ----
    const bool isf32 = (*flag != 0);
    const int gb = blockIdx.x - NSCAN;
    const int mt0 = gb * 4;
    for (int i = tid; i < 2048; i += 256) {
        const int row = i >> 5;
        const int c4 = (i & 31) * 4;
        const int gnode = mt0 * 16 + row;
        const bool gene = (gnode >= ND);
        const void* xr = gene ? xg_r : xd_r;
        const size_t base = (size_t)(gene ? gnode - ND : gnode) * 128 + c4;
        float4 v;
        if (isf32) {
            v = *(const float4*)((const float*)xr + base);
        } else {
            const ushort4 u = *(const ushort4*)((const unsigned short*)xr + base);
            v = make_float4(bu(u.x), bu(u.y), bu(u.z), bu(u.w));
        }
        f16* dst = xls + row * XLSTRIDE + c4;
        dst[0] = (f16)v.x; dst[1] = (f16)v.y; dst[2] = (f16)v.z; dst[3] = (f16)v.w;
    }
    __syncthreads();
    kqv_block_4mt(xls, tid, mt0, Wpd, bpd, Wpg, bpg, tab);

    // ---- scatter epilogue: one satisfied-poll, then strided slice ----
    if (tid == 0) {
        while (atomicAdd(&ready[63], 0) < NSCAN) __builtin_amdgcn_s_sleep(2);
    }
    __syncthreads();
    __threadfence();   // acquire: rp reads below must observe scan's writes
    for (int i = gb * 256 + tid; i < NE; i += NQUAD * 256) {
        if (i < E_DG) {
            edges_g[rp_g[dst_dg[i]] + rank[i]] = src_dg[i] * OCD + 128;              // et0
        } else if (i < EG) {
            const int j = i - E_DG;
            edges_g[rp_g[dst_gg[j]] + rank[i]] = (int)GOFF + src_gg[j] * OCG + 384;  // et2
        } else {
            const int j = i - EG;
            edges_d[rp_d[dst_gd[j]] + rank[i]] = (int)GOFF + src_gd[j] * OCG + 128;  // et1
        }
    }
}

// ---------------------------------------------------------------------------
// Unified gather aggregation (round-3 wave-per-node form -- measured best:
// 43.5us vs 45.3 slot-per-node, 46.9 deep-pipeline). Wave = 1 node, 4 slot
// chains, 2-pair interleave -> 8 records in flight/wave + slot merge.
// No online-max: logits bounded (|a|<~6 in log2 domain), softmax is
// shift-invariant, plain exp2 accumulation is exact enough.
__global__ __launch_bounds__(256) void k_agg(
    const int* __restrict__ rp_g, const int* __restrict__ edges_g,
    const int* __restrict__ rp_d, const int* __restrict__ edges_d,
    const f16* __restrict__ tab, f16* __restrict__ gagg) {
    const int wid = blockIdx.x * 4 + (threadIdx.x >> 6);
    const int lane = threadIdx.x & 63;
    const int slot = lane >> 4, sub = lane & 15;

    int node, row;
    const int *rp, *edges;
    size_t qoff;
    if (wid < NG) {
        node = wid; rp = rp_g; edges = edges_g;
        qoff = GOFF + (size_t)node * OCG;
        row = ND + node;
    } else {
        node = wid - NG; rp = rp_d; edges = edges_d;
        qoff = (size_t)node * OCD;
        row = node;
    }

    union U { f16x8 v; f16x2 p[4]; };
    U q;
    q.v = *(const f16x8*)(tab + qoff + sub * 8);

    float s = 0.f;
    float acc[8];
#pragma unroll
    for (int i = 0; i < 8; i++) acc[i] = 0.f;

    const int r0 = rp[node], r1 = rp[node + 1];
    int e = r0 + slot;

    auto kvload = [&](int rec, U& k, U& v) {
        const f16* p = tab + (size_t)rec + sub * 8;
        k.v = *(const f16x8*)p;
        v.v = *(const f16x8*)(p + 128);
    };

    int recA0 = (e < r1) ? edges[e] : 0;
    int recB0 = (e + 4 < r1) ? edges[e + 4] : 0;
    U kA0, vA0, kB0, vB0;
    kvload(recA0, kA0, vA0);
    kvload(recB0, kB0, vB0);
    int recA1 = (e + 8 < r1) ? edges[e + 8] : 0;
    int recB1 = (e + 12 < r1) ? edges[e + 12] : 0;

    while (e < r1) {
        const int recA2 = (e + 16 < r1) ? edges[e + 16] : 0;
        const int recB2 = (e + 20 < r1) ? edges[e + 20] : 0;
        U kA1, vA1, kB1, vB1;
        kvload(recA1, kA1, vA1);
        kvload(recB1, kB1, vB1);

        float pA = __builtin_amdgcn_fdot2(q.p[0], kA0.p[0], 0.f, false);
        float pB = __builtin_amdgcn_fdot2(q.p[0], kB0.p[0], 0.f, false);
        pA = __builtin_amdgcn_fdot2(q.p[1], kA0.p[1], pA, false);
        pB = __builtin_amdgcn_fdot2(q.p[1], kB0.p[1], pB, false);
        pA = __builtin_amdgcn_fdot2(q.p[2], kA0.p[2], pA, false);
        pB = __builtin_amdgcn_fdot2(q.p[2], kB0.p[2], pB, false);
        pA = __builtin_amdgcn_fdot2(q.p[3], kA0.p[3], pA, false);
        pB = __builtin_amdgcn_fdot2(q.p[3], kB0.p[3], pB, false);
        pA += __shfl_xor(pA, 1);
        pB += __shfl_xor(pB, 1);
        pA += __shfl_xor(pA, 2);
        pB += __shfl_xor(pB, 2);
        const float eaA = exp2f(pA);
        const float eaB = (e + 4 < r1) ? exp2f(pB) : 0.f;
        s += eaA + eaB;
#pragma unroll
        for (int i = 0; i < 8; i++)
            acc[i] = fmaf(eaB, (float)vB0.v[i], fmaf(eaA, (float)vA0.v[i], acc[i]));
        recA0 = recA1; recB0 = recB1; recA1 = recA2; recB1 = recB2;
        kA0 = kA1; vA0 = vA1; kB0 = kB1; vB0 = vB1;
        e += 8;
    }

    // merge the 4 slot-chains (plain sums)
#pragma unroll
    for (int mask = 16; mask <= 32; mask <<= 1) {
        s += __shfl_xor(s, mask);
#pragma unroll
        for (int i = 0; i < 8; i++) acc[i] += __shfl_xor(acc[i], mask);
    }

    const float inv = (s > 0.f) ? (1.f / s) : 0.f;
    if (slot == 0) {
        f16x8 o;
#pragma unroll
        for (int i = 0; i < 8; i++) o[i] = (f16)gelu(acc[i] * inv);
        *(f16x8*)(gagg + (size_t)row * HD + sub * 8) = o;
    }
}

// ---------------------------------------------------------------------------
// Fused layer-0 update + layer-1 KQV GEMM. Block = 64 nodes (4 mtiles).
__global__ __launch_bounds__(256) void k_updgemm(
    const f16* __restrict__ gagg,
    const f16* __restrict__ Wpod0, const f16* __restrict__ Wpog0,
    const float* __restrict__ boutc_d0, const float* __restrict__ boutc_g0,
    const float* __restrict__ gates,   // [0]=d0 [1]=g0
    const void* xd_r, const void* xg_r, const int* __restrict__ flag,
    f16* __restrict__ xball,
    const f16* __restrict__ Wpd1, const float* __restrict__ bpd1,
    const f16* __restrict__ Wpg1, const float* __restrict__ bpg1,
    f16* __restrict__ tab) {
    __shared__ f16 xls[64 * XLSTRIDE];
    const bool isf32 = (*flag != 0);
    const int tid = threadIdx.x;
    const int wv = tid >> 6, lane = tid & 63;
    const int r = lane & 15, q4 = lane >> 4;

    // ---- phase 1: layer-0 update (o = gelu(agg)@Wout0 + b; gate skip) ----
    {
        const int nt = wv & 1, col0 = nt << 6;
        f16x8 B[4][4];
        int prevg = -1;
#pragma unroll 1
        for (int p = 0; p < 2; p++) {
            const int mtl = (wv >> 1) + p * 2;
            const int node0 = (blockIdx.x * 4 + mtl) * 16;
            const bool gene = (node0 >= ND);
            const f16* Wp = gene ? Wpog0 : Wpod0;
            const float* bias = gene ? boutc_g0 : boutc_d0;
            const float g = gates[gene ? 1 : 0];
            if ((int)gene != prevg) {
                prevg = (int)gene;
#pragma unroll
                for (int kb = 0; kb < 4; kb++) {
                    const f16* wb = Wp + ((size_t)kb * 128 + col0 + r) * 32 + q4 * 8;
#pragma unroll
                    for (int t = 0; t < 4; t++) B[kb][t] = *(const f16x8*)(wb + t * 512);
                }
            }
            f32x4 acc[4];
            acc[0] = acc[1] = acc[2] = acc[3] = (f32x4){0.f, 0.f, 0.f, 0.f};
#pragma unroll
            for (int kb = 0; kb < 4; kb++) {
                const f16x8 a = *(const f16x8*)(gagg + (size_t)(node0 + r) * 128 + kb * 32 + q4 * 8);
#pragma unroll
                for (int t = 0; t < 4; t++)
                    acc[t] = __builtin_amdgcn_mfma_f32_16x16x32_f16(B[kb][t], a, acc[t], 0, 0, 0);
            }
            const void* xr = gene ? xg_r : xd_r;
            const int lrow0 = node0 - (gene ? ND : 0);
#pragma unroll
            for (int t = 0; t < 4; t++) {
                const int col = col0 + t * 16 + q4 * 4;
                const f32x4 bb = *(const f32x4*)(bias + col);
                const size_t xbase = (size_t)(lrow0 + r) * 128 + col;
                float xo[4];
                if (isf32) {
                    const f32x4 u = *(const f32x4*)((const float*)xr + xbase);
#pragma unroll
                    for (int reg = 0; reg < 4; reg++) xo[reg] = u[reg];
                } else {
                    const ushort4 u = *(const ushort4*)((const unsigned short*)xr + xbase);
                    xo[0] = bu(u.x); xo[1] = bu(u.y); xo[2] = bu(u.z); xo[3] = bu(u.w);
                }
                f16x4 xv;
#pragma unroll
                for (int reg = 0; reg < 4; reg++) {
                    const float xn = g * (acc[t][reg] + bb[reg]) + (1.f - g) * xo[reg];
                    xv[reg] = (f16)xn;
                }
                *(f16x4*)(xls + (mtl * 16 + r) * XLSTRIDE + col) = xv;
                *(f16x4*)(xball + (size_t)(node0 + r) * 128 + col) = xv;
            }
        }
    }
    __syncthreads();

    // ---- phase 2: layer-1 KQV GEMM from LDS (4-mtile B-reuse) ----
    kqv_block_4mt(xls, tid, blockIdx.x * 4, Wpd1, bpd1, Wpg1, bpg1, tab);
}

// ---------------------------------------------------------------------------
// Final update (layer 1): o = gagg @ Wout1 + b; dout = g*o + (1-g)*x1.
__global__ __launch_bounds__(256) void k_upd1(
    const f16* __restrict__ gagg,
    const f16* __restrict__ Wpod1, const f16* __restrict__ Wpog1,
    const float* __restrict__ boutc_d1, const float* __restrict__ boutc_g1,
    const float* __restrict__ gates,   // [0]=d1 [1]=g1 (pre-offset)
    const f16* __restrict__ xball, float* __restrict__ dout) {
    const int tid = threadIdx.x;
    const int wv = tid >> 6, lane = tid & 63;
    const int r = lane & 15, q4 = lane >> 4;
    const int nt = wv & 1, col0 = nt << 6;
    f16x8 B[4][4];
    int prevg = -1;
#pragma unroll 1
    for (int p = 0; p < 2; p++) {
        const int mtile = blockIdx.x * 4 + (wv >> 1) * 2 + p;
        const int node0 = mtile * 16;
        const bool gene = (node0 >= ND);
        const f16* Wp = gene ? Wpog1 : Wpod1;
        const float* bias = gene ? boutc_g1 : boutc_d1;
        const float g = gates[gene ? 1 : 0];
        if ((int)gene != prevg) {
            prevg = (int)gene;
#pragma unroll
            for (int kb = 0; kb < 4; kb++) {
                const f16* wb = Wp + ((size_t)kb * 128 + col0 + r) * 32 + q4 * 8;
#pragma unroll
                for (int t = 0; t < 4; t++) B[kb][t] = *(const f16x8*)(wb + t * 512);
            }
        }
        f32x4 acc[4];
        acc[0] = acc[1] = acc[2] = acc[3] = (f32x4){0.f, 0.f, 0.f, 0.f};
#pragma unroll
        for (int kb = 0; kb < 4; kb++) {
            const f16x8 a = *(const f16x8*)(gagg + (size_t)(node0 + r) * 128 + kb * 32 + q4 * 8);
#pragma unroll
            for (int t = 0; t < 4; t++)
                acc[t] = __builtin_amdgcn_mfma_f32_16x16x32_f16(B[kb][t], a, acc[t], 0, 0, 0);
        }
#pragma unroll
        for (int t = 0; t < 4; t++) {
            const int col = col0 + t * 16 + q4 * 4;
            const f32x4 bb = *(const f32x4*)(bias + col);
            const size_t idx = (size_t)(node0 + r) * 128 + col;
            const f16x4 xb = *(const f16x4*)(xball + idx);
            f32x4 o;
#pragma unroll
            for (int reg = 0; reg < 4; reg++)
                o[reg] = g * (acc[t][reg] + bb[reg]) + (1.f - g) * (float)xb[reg];
            *(f32x4*)(dout + idx) = o;
        }
    }
}

// ---------------------------------------------------------------------------
static inline size_t alignup(size_t v) { return (v + 15) & ~(size_t)15; }

extern "C" void kernel_launch(void* const* d_in, const int* in_sizes, int n_in,
                              void* d_out, int out_size, void* d_ws, size_t ws_size,
                              hipStream_t stream) {
    (void)in_sizes; (void)n_in; (void)out_size; (void)ws_size;
    const int* src_dg = (const int*)d_in[2];
    const int* dst_dg = (const int*)d_in[3];
    const int* src_gd = (const int*)d_in[4];
    const int* dst_gd = (const int*)d_in[5];
    const int* src_gg = (const int*)d_in[6];
    const int* dst_gg = (const int*)d_in[7];

    // ---- workspace carve-up ----
    float* ws = (float*)d_ws;
    int* flag = (int*)ws; ws += 16;
    int* cnt_g  = (int*)ws; ws += alignup(NG);   // cnt_g||cnt_d contiguous
    int* cnt_d  = (int*)ws; ws += alignup(ND);
    int* rp_g   = (int*)ws; ws += alignup(NG + 1);
    int* rp_d   = (int*)ws; ws += alignup(ND + 1);
    int* rank   = (int*)ws; ws += alignup(NE);
    int* ready  = (int*)ws; ws += 64;
    int* edges_g = (int*)ws; ws += alignup(EG);
    int* edges_d = (int*)ws; ws += alignup(E_GD);
    float* bp_d = ws; ws += alignup((size_t)NLAYER * OCD);
    float* bp_g = ws; ws += alignup((size_t)NLAYER * OCG);
    float* boutc_d = ws; ws += alignup((size_t)NLAYER * 128);
    float* boutc_g = ws; ws += alignup((size_t)NLAYER * 128);
    float* gates = ws; ws += 16;
    f16* Wp_d = (f16*)ws; ws += alignup((size_t)NLAYER * 4 * OCD * 32 / 2);
    f16* Wp_g = (f16*)ws; ws += alignup((size_t)NLAYER * 4 * OCG * 32 / 2);
    f16* Wpod = (f16*)ws; ws += alignup((size_t)NLAYER * 4 * 128 * 32 / 2);
    f16* Wpog = (f16*)ws; ws += alignup((size_t)NLAYER * 4 * 128 * 32 / 2);
    f16* xball = (f16*)ws; ws += alignup((size_t)(ND + NG) * HD / 2);
    f16* gagg  = (f16*)ws; ws += alignup((size_t)(ND + NG) * HD / 2);
    f16* tab   = (f16*)ws; ws += alignup(((size_t)ND * OCD + (size_t)NG * OCG) / 2);

    // 0) zero histogram counters (stream-ordered, graph-capturable)
    hipMemsetAsync(cnt_g, 0, (size_t)(NG + ND) * sizeof(int), stream);
    // 1) mega-prep + fused histogram/rank capture
    k_prep0<<<1281 + NSCAT, 256, 0, stream>>>(
        d_in[0],
        d_in[8], d_in[9], d_in[10], d_in[11],
        d_in[18], d_in[19], d_in[20],
        d_in[12], d_in[14], d_in[13], d_in[15], d_in[16], d_in[17],
        Wp_d, bp_d, Wp_g, bp_g, Wpod, Wpog, boutc_d, boutc_g,
        gates, flag,
        dst_dg, dst_gg, dst_gd, cnt_g, cnt_d, rank, ready);
    // 2) scan (40 blocks) + layer-0 KQV GEMM with scatter epilogue (625)
    k_scangemm0<<<NSCAN + NQUAD, 256, 0, stream>>>(
        cnt_g, cnt_d, ready, rp_g, rp_d,
        d_in[0], d_in[1], flag,
        Wp_d, bp_d, Wp_g, bp_g, tab,
        src_dg, dst_dg, src_gg, dst_gg, src_gd, dst_gd,
        rank, edges_g, edges_d);
    // 3) layer-0 aggregation
    k_agg<<<(NG + ND) / 4, 256, 0, stream>>>(rp_g, edges_g, rp_d, edges_d, tab, gagg);
    // 4) layer-0 update fused with layer-1 KQV GEMM
    k_updgemm<<<NQUAD, 256, 0, stream>>>(
        gagg, Wpod, Wpog, boutc_d, boutc_g, gates,
        d_in[0], d_in[1], flag, xball,
        Wp_d + (size_t)4 * OCD * 32, bp_d + OCD,
        Wp_g + (size_t)4 * OCG * 32, bp_g + OCG, tab);
    // 5) layer-1 aggregation
    k_agg<<<(NG + ND) / 4, 256, 0, stream>>>(rp_g, edges_g, rp_d, edges_d, tab, gagg);
    // 6) final update -> d_out (fp32)
    k_upd1<<<NQUAD, 256, 0, stream>>>(
        gagg, Wpod + (size_t)4 * 128 * 32, Wpog + (size_t)4 * 128 * 32,
        boutc_d + 128, boutc_g + 128, gates + 2, xball, (float*)d_out);
}

// Round 9
// 301.486 us; speedup vs baseline: 1.3248x; 1.3248x over previous
//
#include <hip/hip_runtime.h>
#include <hip/hip_bf16.h>

#define H 4
#define D 32
#define HD 128
#define ND 10000
#define NG 30000
#define E_DG 150000
#define E_GD 150000
#define E_GG 300000
#define NE (E_DG + E_GD + E_GG)
#define EG (E_DG + E_GG)   // edges into gene nodes
#define NLAYER 2
#define NBG 30             // ceil(NG/1024)
#define NBD 10             // ceil(ND/1024)
#define NSCAN (NBG + NBD)
#define OCG 640            // gene table cols:   [q|k1|v1|k2|v2]
#define OCD 384            // disease table cols:[q|k0|v0]
#define GOFF ((size_t)ND * OCD)   // gene rows offset in unified table
#define NSCAT 2344         // scatter / histogram blocks
#define NQUAD 625          // 4-mtile GEMM blocks (2500 mtiles / 4)
#define XLSTRIDE 136       // LDS A-row stride in f16 (mod-32-words = 4 -> 2x/bank-quad)

typedef _Float16 f16;
typedef __attribute__((ext_vector_type(2))) _Float16 f16x2;
typedef __attribute__((ext_vector_type(4))) _Float16 f16x4;
typedef __attribute__((ext_vector_type(8))) _Float16 f16x8;
typedef __attribute__((ext_vector_type(8))) unsigned short u16x8;
typedef __attribute__((ext_vector_type(4))) float f32x4;

__device__ __forceinline__ float bu(unsigned short u) {
    return __uint_as_float(((unsigned)u) << 16);
}
// raw input load with dtype branch (isf32 wave-uniform)
__device__ __forceinline__ float ldraw(const void* p, size_t i, bool isf32) {
    return isf32 ? ((const float*)p)[i] : bu(((const unsigned short*)p)[i]);
}
__device__ __forceinline__ float gelu(float v) {
    const float c = 0.79788456080286536f * (v + 0.044715f * v * v * v);
    return 0.5f * v * (1.0f + tanhf(c));
}

// ---------------------------------------------------------------------------
// Combined-weight fold (rel matrices + prel*scale*log2e into K), raw inputs.
// W reads vectorized (32 contiguous elems -> 4x16B / 8x16B loads).
__device__ __forceinline__ void combine_one(
    int idx, int GENE, bool isf32,
    const void* W, const void* bvec,
    const void* arel, const void* mrel, const void* prel,
    f16* __restrict__ Wp, float* __restrict__ bp) {
    const int OC = GENE ? OCG : OCD;
    const int l = idx / (OC * 128);
    const int rem = idx - l * OC * 128;
    const int col = rem >> 7;
    const int d = rem & 127;
    const int g = col >> 7;           // 0=q, 1/3=k, 2/4=v
    const int jj = col & 127;
    const int h = jj >> 5, f = jj & 31;
    const size_t wbase = (size_t)l * 128 * 384;
    const size_t bbase = (size_t)l * 384;
    float val, bv = 0.f;
    if (g == 0) {
        val = ldraw(W, wbase + d * 384 + 128 + jj, isf32);
        bv = ldraw(bvec, bbase + 128 + jj, isf32);
    } else {
        const int et = GENE ? ((g <= 2) ? 1 : 2) : 0;
        const bool isk = (g & 1);
        const void* mat = isk ? arel : mrel;
        const size_t mbase = (((size_t)(l * 3 + et) * H + h) << 10) + f;
        const int sb = isk ? 0 : 256;
        const size_t wrow = wbase + d * 384 + sb + h * 32;   // 32 contiguous elems
        float wv[32];
        if (isf32) {
            const float* wp = (const float*)W + wrow;
#pragma unroll
            for (int j = 0; j < 8; j++) {
                const f32x4 u = *(const f32x4*)(wp + j * 4);
#pragma unroll
                for (int t = 0; t < 4; t++) wv[j * 4 + t] = u[t];
            }
        } else {
            const unsigned short* wp = (const unsigned short*)W + wrow;
#pragma unroll
            for (int j = 0; j < 4; j++) {
                const u16x8 u = *(const u16x8*)(wp + j * 8);
#pragma unroll
                for (int t = 0; t < 8; t++) wv[j * 8 + t] = bu(u[t]);
            }
        }
        val = 0.f;
#pragma unroll
        for (int dd = 0; dd < 32; dd++)
            val += wv[dd] * ldraw(mat, mbase + dd * 32, isf32);
        if (d == 0)
            for (int dd = 0; dd < 32; dd++)
                bv += ldraw(bvec, bbase + sb + h * 32 + dd, isf32) *
                      ldraw(mat, mbase + dd * 32, isf32);
        if (isk) {
            const float sc = ldraw(prel, (size_t)(l * 3 + et) * H + h, isf32) *
                             (0.17677669529663689f * 1.4426950408889634f);
            val *= sc;
            bv *= sc;
        }
    }
    Wp[(size_t)l * 4 * OC * 32 + ((size_t)(d >> 5) * OC + col) * 32 + (d & 31)] = (f16)val;
    if (d == 0) bp[l * OC + col] = bv;
}

// ---------------------------------------------------------------------------
// Mega-prep: self-detect dtype, fold+pack all weights, zero ready, convert
// bout, compute sigmoid(skip) gates, publish flag. Blocks >=1281 run the
// histogram fused in (cnt zeroed by hipMemsetAsync before this kernel), and
// capture each edge's within-bucket rank from the atomicAdd return value.
__global__ __launch_bounds__(256) void k_prep0(
    const void* x0,
    const void* wkqvd_r, const void* bkqvd_r,
    const void* wkqvg_r, const void* bkqvg_r,
    const void* arel_r, const void* mrel_r, const void* prel_r,
    const void* woutd_r, const void* woutg_r,
    const void* boutd_r, const void* boutg_r,
    const void* skipd_r, const void* skipg_r,
    f16* __restrict__ Wp_d, float* __restrict__ bp_d,
    f16* __restrict__ Wp_g, float* __restrict__ bp_g,
    f16* __restrict__ Wpod, f16* __restrict__ Wpog,
    float* __restrict__ boutc_d, float* __restrict__ boutc_g,
    float* __restrict__ gates, int* __restrict__ flag,
    const int* __restrict__ dst_dg, const int* __restrict__ dst_gg,
    const int* __restrict__ dst_gd,
    int* __restrict__ cnt_g, int* __restrict__ cnt_d,
    int* __restrict__ rank, int* __restrict__ ready) {
    const int tid = threadIdx.x;
    const int b = blockIdx.x;
    if (b >= 1281) {
        // fused histogram + rank capture
        const int i = (b - 1281) * 256 + tid;
        if (i < E_DG) rank[i] = atomicAdd(cnt_g + dst_dg[i], 1);
        else if (i < EG) rank[i] = atomicAdd(cnt_g + dst_gg[i - E_DG], 1);
        else if (i < NE) rank[i] = atomicAdd(cnt_d + dst_gd[i - EG], 1);
        return;
    }
    __shared__ int sbad;
    if (tid == 0) sbad = 0;
    __syncthreads();
    {
        const unsigned short* xs = (const unsigned short*)x0;
        int bad = 0;
        for (int i = tid; i < 1024; i += 256)
            if (!(fabsf(bu(xs[i])) < 1e6f)) bad = 1;
        if (bad) sbad = 1;   // benign race
    }
    __syncthreads();
    const bool isf32 = (sbad != 0);

    if (b < 1280) {
        int idx = b * 256 + tid;
        const int nd = NLAYER * OCD * 128;
        const int ng = NLAYER * OCG * 128;
        const int np = 2 * NLAYER * 128 * 128;
        if (idx < nd) {
            combine_one(idx, 0, isf32, wkqvd_r, bkqvd_r, arel_r, mrel_r, prel_r, Wp_d, bp_d);
        } else if ((idx -= nd) < ng) {
            combine_one(idx, 1, isf32, wkqvg_r, bkqvg_r, arel_r, mrel_r, prel_r, Wp_g, bp_g);
        } else if ((idx -= ng) < np) {
            const int type = idx >= NLAYER * 128 * 128;
            int rem = idx - type * NLAYER * 128 * 128;
            const int l = rem / (128 * 128);
            rem -= l * 128 * 128;
            const int d = rem >> 7, col = rem & 127;
            const float w = ldraw(type ? woutg_r : woutd_r,
                                  (size_t)l * 128 * 128 + d * 128 + col, isf32);
            f16* out = (type ? Wpog : Wpod) +
                ((size_t)l * 4 + (d >> 5)) * 128 * 32 + col * 32 + (d & 31);
            *out = (f16)w;
        }
    } else {   // b == 1280
        if (tid < NSCAN) ready[tid] = 0;
        if (tid == 0) {
            flag[0] = isf32 ? 1 : 0;
            gates[0] = 1.f / (1.f + expf(-ldraw(skipd_r, 0, isf32)));
            gates[1] = 1.f / (1.f + expf(-ldraw(skipg_r, 0, isf32)));
            gates[2] = 1.f / (1.f + expf(-ldraw(skipd_r, 1, isf32)));
            gates[3] = 1.f / (1.f + expf(-ldraw(skipg_r, 1, isf32)));
        }
        for (int i = tid; i < NLAYER * 128; i += 256) {
            boutc_d[i] = ldraw(boutd_r, i, isf32);
            boutc_g[i] = ldraw(boutg_r, i, isf32);
        }
    }
}

// ---------------------------------------------------------------------------
// 4-mtile KQV GEMM over a 64-row LDS A tile. Each wave loads a 64-col B
// panel ONCE into registers and applies it to all 4 mtiles. Swapped-mfma
// layout (C^T): row=lane&15, 4 consecutive cols per acc reg -> f16x4 stores.
__device__ __forceinline__ void kqv_block_4mt(
    const f16* xls, int tid, int mt0,
    const f16* __restrict__ Wpd, const float* __restrict__ bpd,
    const f16* __restrict__ Wpg, const float* __restrict__ bpg,
    f16* __restrict__ tab) {
    const int wv = tid >> 6, lane = tid & 63;
    const int r = lane & 15, q4 = lane >> 4;
    const bool g0 = (mt0 * 16 >= ND);
    const bool g3 = ((mt0 + 3) * 16 >= ND);
    if (g0 == g3) {
        // uniform-type quad: B-reuse path
        const bool gene = g0;
        const int OC = gene ? OCG : OCD;
        const f16* Wp = gene ? Wpg : Wpd;
        const float* bias = gene ? bpg : bpd;
        f16* out = gene ? (tab + GOFF) : tab;
        const int trow0 = mt0 * 16 - (gene ? ND : 0);
        const int nt = gene ? 10 : 6;
        for (int ntl = wv; ntl < nt; ntl += 4) {
            const int col0 = ntl << 6;
            f16x8 B[4][4];
#pragma unroll
            for (int kb = 0; kb < 4; kb++) {
                const f16* wb = Wp + ((size_t)kb * OC + col0 + r) * 32 + q4 * 8;
#pragma unroll
                for (int t = 0; t < 4; t++) B[kb][t] = *(const f16x8*)(wb + t * 512);
            }
#pragma unroll 1
            for (int mtl = 0; mtl < 4; mtl++) {
                f32x4 acc[4];
                acc[0] = acc[1] = acc[2] = acc[3] = (f32x4){0.f, 0.f, 0.f, 0.f};
#pragma unroll
                for (int kb = 0; kb < 4; kb++) {
                    const f16x8 a = *(const f16x8*)(xls + (mtl * 16 + r) * XLSTRIDE + kb * 32 + q4 * 8);
#pragma unroll
                    for (int t = 0; t < 4; t++)
                        acc[t] = __builtin_amdgcn_mfma_f32_16x16x32_f16(B[kb][t], a, acc[t], 0, 0, 0);
                }
#pragma unroll
                for (int t = 0; t < 4; t++) {
                    const int col = col0 + t * 16 + q4 * 4;
                    const f32x4 bb = *(const f32x4*)(bias + col);
                    f16x4 o;
#pragma unroll
                    for (int reg = 0; reg < 4; reg++)
                        o[reg] = (f16)(acc[t][reg] + bb[reg]);
                    *(f16x4*)(out + (size_t)(trow0 + mtl * 16 + r) * OC + col) = o;
                }
            }
        }
    } else {
        // mixed quad (1 block at the d/g boundary): per-mtile path
        for (int mtl = 0; mtl < 4; mtl++) {
            const int node0 = (mt0 + mtl) * 16;
            const bool gene = (node0 >= ND);
            const int OC = gene ? OCG : OCD;
            const f16* Wp = gene ? Wpg : Wpd;
            const float* bias = gene ? bpg : bpd;
            f16* out = gene ? (tab + GOFF) : tab;
            const int trow0 = node0 - (gene ? ND : 0);
            const int nt = gene ? 10 : 6;
            for (int ntl = wv; ntl < nt; ntl += 4) {
                const int col0 = ntl << 6;
                f32x4 acc[4];
                acc[0] = acc[1] = acc[2] = acc[3] = (f32x4){0.f, 0.f, 0.f, 0.f};
#pragma unroll
                for (int kb = 0; kb < 4; kb++) {
                    const f16x8 a = *(const f16x8*)(xls + (mtl * 16 + r) * XLSTRIDE + kb * 32 + q4 * 8);
                    const f16* wb = Wp + ((size_t)kb * OC + col0 + r) * 32 + q4 * 8;
#pragma unroll
                    for (int t = 0; t < 4; t++) {
                        const f16x8 bt = *(const f16x8*)(wb + t * 512);
                        acc[t] = __builtin_amdgcn_mfma_f32_16x16x32_f16(bt, a, acc[t], 0, 0, 0);
                    }
                }
#pragma unroll
                for (int t = 0; t < 4; t++) {
                    const int col = col0 + t * 16 + q4 * 4;
                    const f32x4 bb = *(const f32x4*)(bias + col);
                    f16x4 o;
#pragma unroll
                    for (int reg = 0; reg < 4; reg++)
                        o[reg] = (f16)(acc[t][reg] + bb[reg]);
                    *(f16x4*)(out + (size_t)(trow0 + r) * OC + col) = o;
                }
            }
        }
    }
}

// ---------------------------------------------------------------------------
// Fused: decoupled-lookback scan (blocks [0,NSCAN)) + layer-0 KQV GEMM
// (blocks [NSCAN,..), 4 mtiles each). Scan blocks have the lowest blockIdx
// so they are resident before any gemm block (lookback stays deadlock-free).
// Scatter is a SEPARATE dispatch (r4/r7/r8: all intra-kernel fusions of the
// scatter regressed -- poller/writer cache-line contention or worker
// mismatch; the ~5us stream dependency is cheaper).
__global__ __launch_bounds__(256) void k_scangemm0(
    const int* __restrict__ cnt_g, const int* __restrict__ cnt_d,
    int* __restrict__ ready,
    int* __restrict__ rp_g, int* __restrict__ rp_d,
    const void* xd_r, const void* xg_r, const int* __restrict__ flag,
    const f16* __restrict__ Wpd, const float* __restrict__ bpd,
    const f16* __restrict__ Wpg, const float* __restrict__ bpg,
    f16* __restrict__ tab) {
    __shared__ int sdata[256];
    __shared__ int red2[256];
    __shared__ int s_off;
    __shared__ f16 xls[64 * XLSTRIDE];
    const int tid = threadIdx.x;
    if (blockIdx.x < NSCAN) {
        const int b = blockIdx.x;
        const bool isg = (b < NBG);
        const int* cnt = isg ? cnt_g : cnt_d;
        int* rp = isg ? rp_g : rp_d;
        const int n = isg ? NG : ND;
        const int lb = isg ? b : (b - NBG);
        const int i0 = lb * 1024 + tid * 4;
        int v[4];
        int t = 0;
#pragma unroll
        for (int j = 0; j < 4; j++) {
            v[j] = (i0 + j < n) ? cnt[i0 + j] : 0;
            t += v[j];
        }
        sdata[tid] = t;
        __syncthreads();
        for (int d = 1; d < 256; d <<= 1) {
            const int u = (tid >= d) ? sdata[tid - d] : 0;
            __syncthreads();
            sdata[tid] += u;
            __syncthreads();
        }
        const int total = sdata[255];
        if (tid == 0) atomicExch(&ready[b], total + 1);
        const int p0 = isg ? 0 : NBG;
        const int npred = b - p0;
        int part = 0;
        for (int i = tid; i < npred; i += 256) {
            int vv;
            do { vv = atomicAdd(&ready[p0 + i], 0); } while (vv == 0);
            part += vv - 1;
        }
        red2[tid] = part;
        __syncthreads();
        for (int d = 128; d > 0; d >>= 1) {
            if (tid < d) red2[tid] += red2[tid + d];
            __syncthreads();
        }
        if (tid == 0) s_off = red2[0];
        __syncthreads();
        int run = s_off + sdata[tid] - t;
#pragma unroll
        for (int j = 0; j < 4; j++) {
            if (i0 + j < n) {
                run += v[j];
                rp[i0 + j + 1] = run;
            }
        }
        if (tid == 0 && lb == 0) rp[0] = 0;
        return;
    }
    // ---- gemm0: 4 mtiles, 64-row LDS A stage ----
    const bool isf32 = (*flag != 0);
    const int mt0 = (blockIdx.x - NSCAN) * 4;
    for (int i = tid; i < 2048; i += 256) {
        const int row = i >> 5;
        const int c4 = (i & 31) * 4;
        const int gnode = mt0 * 16 + row;
        const bool gene = (gnode >= ND);
        const void* xr = gene ? xg_r : xd_r;
        const size_t base = (size_t)(gene ? gnode - ND : gnode) * 128 + c4;
        float4 v;
        if (isf32) {
            v = *(const float4*)((const float*)xr + base);
        } else {
            const ushort4 u = *(const ushort4*)((const unsigned short*)xr + base);
            v = make_float4(bu(u.x), bu(u.y), bu(u.z), bu(u.w));
        }
        f16* dst = xls + row * XLSTRIDE + c4;
        dst[0] = (f16)v.x; dst[1] = (f16)v.y; dst[2] = (f16)v.z; dst[3] = (f16)v.w;
    }
    __syncthreads();
    kqv_block_4mt(xls, tid, mt0, Wpd, bpd, Wpg, bpg, tab);
}

// ---------------------------------------------------------------------------
// Atomic-free scatter: pos = rp[dst] + rank (rank captured in prep0's fused
// histogram). Separate dispatch: measured faster than every fusion attempt.
__global__ __launch_bounds__(256) void k_scatter(
    const int* __restrict__ src_dg, const int* __restrict__ dst_dg,
    const int* __restrict__ src_gg, const int* __restrict__ dst_gg,
    const int* __restrict__ src_gd, const int* __restrict__ dst_gd,
    const int* __restrict__ rp_g, const int* __restrict__ rp_d,
    const int* __restrict__ rank,
    int* __restrict__ edges_g, int* __restrict__ edges_d) {
    const int i = blockIdx.x * 256 + threadIdx.x;
    if (i < E_DG) {
        edges_g[rp_g[dst_dg[i]] + rank[i]] = src_dg[i] * OCD + 128;              // et0: d->g
    } else if (i < EG) {
        const int j = i - E_DG;
        edges_g[rp_g[dst_gg[j]] + rank[i]] = (int)GOFF + src_gg[j] * OCG + 384;  // et2: g->g
    } else if (i < NE) {
        const int j = i - EG;
        edges_d[rp_d[dst_gd[j]] + rank[i]] = (int)GOFF + src_gd[j] * OCG + 128;  // et1: g->d
    }
}

// ---------------------------------------------------------------------------
// Unified gather aggregation (wave-per-node: measured best of 3 variants --
// 43.5us vs 45.3 slot-per-node vs 46.9 deep-pipeline; the kernel is pinned
// at the ~3.2 TB/s random-512B-gather fill ceiling regardless of structure).
// No online-max: logits bounded (|a|<~6 in log2 domain), softmax is
// shift-invariant, plain exp2 accumulation is exact enough.
__global__ __launch_bounds__(256) void k_agg(
    const int* __restrict__ rp_g, const int* __restrict__ edges_g,
    const int* __restrict__ rp_d, const int* __restrict__ edges_d,
    const f16* __restrict__ tab, f16* __restrict__ gagg) {
    const int wid = blockIdx.x * 4 + (threadIdx.x >> 6);
    const int lane = threadIdx.x & 63;
    const int slot = lane >> 4, sub = lane & 15;

    int node, row;
    const int *rp, *edges;
    size_t qoff;
    if (wid < NG) {
        node = wid; rp = rp_g; edges = edges_g;
        qoff = GOFF + (size_t)node * OCG;
        row = ND + node;
    } else {
        node = wid - NG; rp = rp_d; edges = edges_d;
        qoff = (size_t)node * OCD;
        row = node;
    }

    union U { f16x8 v; f16x2 p[4]; };
    U q;
    q.v = *(const f16x8*)(tab + qoff + sub * 8);

    float s = 0.f;
    float acc[8];
#pragma unroll
    for (int i = 0; i < 8; i++) acc[i] = 0.f;

    const int r0 = rp[node], r1 = rp[node + 1];
    int e = r0 + slot;

    auto kvload = [&](int rec, U& k, U& v) {
        const f16* p = tab + (size_t)rec + sub * 8;
        k.v = *(const f16x8*)p;
        v.v = *(const f16x8*)(p + 128);
    };

    int recA0 = (e < r1) ? edges[e] : 0;
    int recB0 = (e + 4 < r1) ? edges[e + 4] : 0;
    U kA0, vA0, kB0, vB0;
    kvload(recA0, kA0, vA0);
    kvload(recB0, kB0, vB0);
    int recA1 = (e + 8 < r1) ? edges[e + 8] : 0;
    int recB1 = (e + 12 < r1) ? edges[e + 12] : 0;

    while (e < r1) {
        const int recA2 = (e + 16 < r1) ? edges[e + 16] : 0;
        const int recB2 = (e + 20 < r1) ? edges[e + 20] : 0;
        U kA1, vA1, kB1, vB1;
        kvload(recA1, kA1, vA1);
        kvload(recB1, kB1, vB1);

        float pA = __builtin_amdgcn_fdot2(q.p[0], kA0.p[0], 0.f, false);
        float pB = __builtin_amdgcn_fdot2(q.p[0], kB0.p[0], 0.f, false);
        pA = __builtin_amdgcn_fdot2(q.p[1], kA0.p[1], pA, false);
        pB = __builtin_amdgcn_fdot2(q.p[1], kB0.p[1], pB, false);
        pA = __builtin_amdgcn_fdot2(q.p[2], kA0.p[2], pA, false);
        pB = __builtin_amdgcn_fdot2(q.p[2], kB0.p[2], pB, false);
        pA = __builtin_amdgcn_fdot2(q.p[3], kA0.p[3], pA, false);
        pB = __builtin_amdgcn_fdot2(q.p[3], kB0.p[3], pB, false);
        pA += __shfl_xor(pA, 1);
        pB += __shfl_xor(pB, 1);
        pA += __shfl_xor(pA, 2);
        pB += __shfl_xor(pB, 2);
        const float eaA = exp2f(pA);
        const float eaB = (e + 4 < r1) ? exp2f(pB) : 0.f;
        s += eaA + eaB;
#pragma unroll
        for (int i = 0; i < 8; i++)
            acc[i] = fmaf(eaB, (float)vB0.v[i], fmaf(eaA, (float)vA0.v[i], acc[i]));
        recA0 = recA1; recB0 = recB1; recA1 = recA2; recB1 = recB2;
        kA0 = kA1; vA0 = vA1; kB0 = kB1; vB0 = vB1;
        e += 8;
    }

    // merge the 4 slot-chains (plain sums)
#pragma unroll
    for (int mask = 16; mask <= 32; mask <<= 1) {
        s += __shfl_xor(s, mask);
#pragma unroll
        for (int i = 0; i < 8; i++) acc[i] += __shfl_xor(acc[i], mask);
    }

    const float inv = (s > 0.f) ? (1.f / s) : 0.f;
    if (slot == 0) {
        f16x8 o;
#pragma unroll
        for (int i = 0; i < 8; i++) o[i] = (f16)gelu(acc[i] * inv);
        *(f16x8*)(gagg + (size_t)row * HD + sub * 8) = o;
    }
}

// ---------------------------------------------------------------------------
// Fused layer-0 update + layer-1 KQV GEMM. Block = 64 nodes (4 mtiles).
__global__ __launch_bounds__(256) void k_updgemm(
    const f16* __restrict__ gagg,
    const f16* __restrict__ Wpod0, const f16* __restrict__ Wpog0,
    const float* __restrict__ boutc_d0, const float* __restrict__ boutc_g0,
    const float* __restrict__ gates,   // [0]=d0 [1]=g0
    const void* xd_r, const void* xg_r, const int* __restrict__ flag,
    f16* __restrict__ xball,
    const f16* __restrict__ Wpd1, const float* __restrict__ bpd1,
    const f16* __restrict__ Wpg1, const float* __restrict__ bpg1,
    f16* __restrict__ tab) {
    __shared__ f16 xls[64 * XLSTRIDE];
    const bool isf32 = (*flag != 0);
    const int tid = threadIdx.x;
    const int wv = tid >> 6, lane = tid & 63;
    const int r = lane & 15, q4 = lane >> 4;

    // ---- phase 1: layer-0 update (o = gelu(agg)@Wout0 + b; gate skip) ----
    {
        const int nt = wv & 1, col0 = nt << 6;
        f16x8 B[4][4];
        int prevg = -1;
#pragma unroll 1
        for (int p = 0; p < 2; p++) {
            const int mtl = (wv >> 1) + p * 2;
            const int node0 = (blockIdx.x * 4 + mtl) * 16;
            const bool gene = (node0 >= ND);
            const f16* Wp = gene ? Wpog0 : Wpod0;
            const float* bias = gene ? boutc_g0 : boutc_d0;
            const float g = gates[gene ? 1 : 0];
            if ((int)gene != prevg) {
                prevg = (int)gene;
#pragma unroll
                for (int kb = 0; kb < 4; kb++) {
                    const f16* wb = Wp + ((size_t)kb * 128 + col0 + r) * 32 + q4 * 8;
#pragma unroll
                    for (int t = 0; t < 4; t++) B[kb][t] = *(const f16x8*)(wb + t * 512);
                }
            }
            f32x4 acc[4];
            acc[0] = acc[1] = acc[2] = acc[3] = (f32x4){0.f, 0.f, 0.f, 0.f};
#pragma unroll
            for (int kb = 0; kb < 4; kb++) {
                const f16x8 a = *(const f16x8*)(gagg + (size_t)(node0 + r) * 128 + kb * 32 + q4 * 8);
#pragma unroll
                for (int t = 0; t < 4; t++)
                    acc[t] = __builtin_amdgcn_mfma_f32_16x16x32_f16(B[kb][t], a, acc[t], 0, 0, 0);
            }
            const void* xr = gene ? xg_r : xd_r;
            const int lrow0 = node0 - (gene ? ND : 0);
#pragma unroll
            for (int t = 0; t < 4; t++) {
                const int col = col0 + t * 16 + q4 * 4;
                const f32x4 bb = *(const f32x4*)(bias + col);
                const size_t xbase = (size_t)(lrow0 + r) * 128 + col;
                float xo[4];
                if (isf32) {
                    const f32x4 u = *(const f32x4*)((const float*)xr + xbase);
#pragma unroll
                    for (int reg = 0; reg < 4; reg++) xo[reg] = u[reg];
                } else {
                    const ushort4 u = *(const ushort4*)((const unsigned short*)xr + xbase);
                    xo[0] = bu(u.x); xo[1] = bu(u.y); xo[2] = bu(u.z); xo[3] = bu(u.w);
                }
                f16x4 xv;
#pragma unroll
                for (int reg = 0; reg < 4; reg++) {
                    const float xn = g * (acc[t][reg] + bb[reg]) + (1.f - g) * xo[reg];
                    xv[reg] = (f16)xn;
                }
                *(f16x4*)(xls + (mtl * 16 + r) * XLSTRIDE + col) = xv;
                *(f16x4*)(xball + (size_t)(node0 + r) * 128 + col) = xv;
            }
        }
    }
    __syncthreads();

    // ---- phase 2: layer-1 KQV GEMM from LDS (4-mtile B-reuse) ----
    kqv_block_4mt(xls, tid, blockIdx.x * 4, Wpd1, bpd1, Wpg1, bpg1, tab);
}

// ---------------------------------------------------------------------------
// Final update (layer 1): o = gagg @ Wout1 + b; dout = g*o + (1-g)*x1.
__global__ __launch_bounds__(256) void k_upd1(
    const f16* __restrict__ gagg,
    const f16* __restrict__ Wpod1, const f16* __restrict__ Wpog1,
    const float* __restrict__ boutc_d1, const float* __restrict__ boutc_g1,
    const float* __restrict__ gates,   // [0]=d1 [1]=g1 (pre-offset)
    const f16* __restrict__ xball, float* __restrict__ dout) {
    const int tid = threadIdx.x;
    const int wv = tid >> 6, lane = tid & 63;
    const int r = lane & 15, q4 = lane >> 4;
    const int nt = wv & 1, col0 = nt << 6;
    f16x8 B[4][4];
    int prevg = -1;
#pragma unroll 1
    for (int p = 0; p < 2; p++) {
        const int mtile = blockIdx.x * 4 + (wv >> 1) * 2 + p;
        const int node0 = mtile * 16;
        const bool gene = (node0 >= ND);
        const f16* Wp = gene ? Wpog1 : Wpod1;
        const float* bias = gene ? boutc_g1 : boutc_d1;
        const float g = gates[gene ? 1 : 0];
        if ((int)gene != prevg) {
            prevg = (int)gene;
#pragma unroll
            for (int kb = 0; kb < 4; kb++) {
                const f16* wb = Wp + ((size_t)kb * 128 + col0 + r) * 32 + q4 * 8;
#pragma unroll
                for (int t = 0; t < 4; t++) B[kb][t] = *(const f16x8*)(wb + t * 512);
            }
        }
        f32x4 acc[4];
        acc[0] = acc[1] = acc[2] = acc[3] = (f32x4){0.f, 0.f, 0.f, 0.f};
#pragma unroll
        for (int kb = 0; kb < 4; kb++) {
            const f16x8 a = *(const f16x8*)(gagg + (size_t)(node0 + r) * 128 + kb * 32 + q4 * 8);
#pragma unroll
            for (int t = 0; t < 4; t++)
                acc[t] = __builtin_amdgcn_mfma_f32_16x16x32_f16(B[kb][t], a, acc[t], 0, 0, 0);
        }
#pragma unroll
        for (int t = 0; t < 4; t++) {
            const int col = col0 + t * 16 + q4 * 4;
            const f32x4 bb = *(const f32x4*)(bias + col);
            const size_t idx = (size_t)(node0 + r) * 128 + col;
            const f16x4 xb = *(const f16x4*)(xball + idx);
            f32x4 o;
#pragma unroll
            for (int reg = 0; reg < 4; reg++)
                o[reg] = g * (acc[t][reg] + bb[reg]) + (1.f - g) * (float)xb[reg];
            *(f32x4*)(dout + idx) = o;
        }
    }
}

// ---------------------------------------------------------------------------
static inline size_t alignup(size_t v) { return (v + 15) & ~(size_t)15; }

extern "C" void kernel_launch(void* const* d_in, const int* in_sizes, int n_in,
                              void* d_out, int out_size, void* d_ws, size_t ws_size,
                              hipStream_t stream) {
    (void)in_sizes; (void)n_in; (void)out_size; (void)ws_size;
    const int* src_dg = (const int*)d_in[2];
    const int* dst_dg = (const int*)d_in[3];
    const int* src_gd = (const int*)d_in[4];
    const int* dst_gd = (const int*)d_in[5];
    const int* src_gg = (const int*)d_in[6];
    const int* dst_gg = (const int*)d_in[7];

    // ---- workspace carve-up ----
    float* ws = (float*)d_ws;
    int* flag = (int*)ws; ws += 16;
    int* cnt_g  = (int*)ws; ws += alignup(NG);   // cnt_g||cnt_d contiguous
    int* cnt_d  = (int*)ws; ws += alignup(ND);
    int* rp_g   = (int*)ws; ws += alignup(NG + 1);
    int* rp_d   = (int*)ws; ws += alignup(ND + 1);
    int* rank   = (int*)ws; ws += alignup(NE);
    int* ready  = (int*)ws; ws += 64;
    int* edges_g = (int*)ws; ws += alignup(EG);
    int* edges_d = (int*)ws; ws += alignup(E_GD);
    float* bp_d = ws; ws += alignup((size_t)NLAYER * OCD);
    float* bp_g = ws; ws += alignup((size_t)NLAYER * OCG);
    float* boutc_d = ws; ws += alignup((size_t)NLAYER * 128);
    float* boutc_g = ws; ws += alignup((size_t)NLAYER * 128);
    float* gates = ws; ws += 16;
    f16* Wp_d = (f16*)ws; ws += alignup((size_t)NLAYER * 4 * OCD * 32 / 2);
    f16* Wp_g = (f16*)ws; ws += alignup((size_t)NLAYER * 4 * OCG * 32 / 2);
    f16* Wpod = (f16*)ws; ws += alignup((size_t)NLAYER * 4 * 128 * 32 / 2);
    f16* Wpog = (f16*)ws; ws += alignup((size_t)NLAYER * 4 * 128 * 32 / 2);
    f16* xball = (f16*)ws; ws += alignup((size_t)(ND + NG) * HD / 2);
    f16* gagg  = (f16*)ws; ws += alignup((size_t)(ND + NG) * HD / 2);
    f16* tab   = (f16*)ws; ws += alignup(((size_t)ND * OCD + (size_t)NG * OCG) / 2);

    // 0) zero histogram counters (stream-ordered, graph-capturable)
    hipMemsetAsync(cnt_g, 0, (size_t)(NG + ND) * sizeof(int), stream);
    // 1) mega-prep + fused histogram/rank capture
    k_prep0<<<1281 + NSCAT, 256, 0, stream>>>(
        d_in[0],
        d_in[8], d_in[9], d_in[10], d_in[11],
        d_in[18], d_in[19], d_in[20],
        d_in[12], d_in[14], d_in[13], d_in[15], d_in[16], d_in[17],
        Wp_d, bp_d, Wp_g, bp_g, Wpod, Wpog, boutc_d, boutc_g,
        gates, flag,
        dst_dg, dst_gg, dst_gd, cnt_g, cnt_d, rank, ready);
    // 2) scan (40 blocks) overlapped with layer-0 KQV GEMM (625 blocks)
    k_scangemm0<<<NSCAN + NQUAD, 256, 0, stream>>>(
        cnt_g, cnt_d, ready, rp_g, rp_d,
        d_in[0], d_in[1], flag,
        Wp_d, bp_d, Wp_g, bp_g, tab);
    // 3) atomic-free scatter
    k_scatter<<<NSCAT, 256, 0, stream>>>(
        src_dg, dst_dg, src_gg, dst_gg, src_gd, dst_gd,
        rp_g, rp_d, rank, edges_g, edges_d);
    // 4) layer-0 aggregation
    k_agg<<<(NG + ND) / 4, 256, 0, stream>>>(rp_g, edges_g, rp_d, edges_d, tab, gagg);
    // 5) layer-0 update fused with layer-1 KQV GEMM
    k_updgemm<<<NQUAD, 256, 0, stream>>>(
        gagg, Wpod, Wpog, boutc_d, boutc_g, gates,
        d_in[0], d_in[1], flag, xball,
        Wp_d + (size_t)4 * OCD * 32, bp_d + OCD,
        Wp_g + (size_t)4 * OCG * 32, bp_g + OCG, tab);
    // 6) layer-1 aggregation
    k_agg<<<(NG + ND) / 4, 256, 0, stream>>>(rp_g, edges_g, rp_d, edges_d, tab, gagg);
    // 7) final update -> d_out (fp32)
    k_upd1<<<NQUAD, 256, 0, stream>>>(
        gagg, Wpod + (size_t)4 * 128 * 32, Wpog + (size_t)4 * 128 * 32,
        boutc_d + 128, boutc_g + 128, gates + 2, xball, (float*)d_out);
}